// Round 4
// baseline (519.515 us; speedup 1.0000x reference)
//
#include <hip/hip_runtime.h>
#include <hip/hip_bf16.h>

typedef __bf16 bf16;
typedef __bf16 bf16x8 __attribute__((ext_vector_type(8)));
typedef __bf16 bf16x4 __attribute__((ext_vector_type(4)));
typedef float f32x4 __attribute__((ext_vector_type(4)));

#define AS1 __attribute__((address_space(1)))
#define AS3 __attribute__((address_space(3)))

static __device__ __forceinline__ void gl_lds16(const bf16* g, char* lds) {
  __builtin_amdgcn_global_load_lds((const AS1 void*)g, (AS3 void*)lds, 16, 0, 0);
}

// ---------------- fp32 -> bf16 convert (x) ----------------
__global__ void conv_k(const float* __restrict__ in, bf16* __restrict__ out) {
  int t = blockIdx.x * blockDim.x + threadIdx.x;
  f32x4 v = *(const f32x4*)(in + (size_t)t * 4);
  bf16x4 o;
#pragma unroll
  for (int j = 0; j < 4; ++j) o[j] = (bf16)v[j];
  *(bf16x4*)(out + (size_t)t * 4) = o;
}

// ------- weight transpose+convert: out[c][r] = (bf16)in[r][c] -------
__global__ void transpose_k(const float* __restrict__ in, bf16* __restrict__ out,
                            int R, int C) {
  __shared__ float t[32][33];
  int c0 = blockIdx.x * 32, r0 = blockIdx.y * 32;
  int tx = threadIdx.x, ty = threadIdx.y;  // 32 x 8
#pragma unroll
  for (int i = 0; i < 32; i += 8) t[ty + i][tx] = in[(size_t)(r0 + ty + i) * C + c0 + tx];
  __syncthreads();
#pragma unroll
  for (int i = 0; i < 32; i += 8)
    out[(size_t)(c0 + ty + i) * R + r0 + tx] = (bf16)t[tx][ty + i];
}

// ---------------- GEMM: C[M,N] = A[M,K] @ BT[N,K]^T (+bias,+res,relu) ----------------
// 128x128 tile, BK=64, 4 waves (2x2), 16x16x32 bf16 MFMA.
// LDS rows are 128B; element (r,k) lives at byte r*128 + ((k*2) ^ ((r&7)<<4)).
// global_load_lds writes linearly, so the global SOURCE address is inverse-swizzled.
template <bool BIAS, bool RES, bool RELU>
__global__ __launch_bounds__(256, 2) void gemm_k(
    const bf16* __restrict__ A, const bf16* __restrict__ BT,
    const float* __restrict__ bias, const bf16* __restrict__ res,
    bf16* __restrict__ C, int M, int N, int K) {
  __shared__ alignas(16) char As[128 * 128];
  __shared__ alignas(16) char Bs[128 * 128];
  const int tid = threadIdx.x;
  const int lane = tid & 63, wid = tid >> 6;
  const int wm = wid >> 1, wn = wid & 1;
  const int row0 = blockIdx.y * 128, col0 = blockIdx.x * 128;
  const int r16 = lane & 15;
  const int kb16 = (lane >> 4) * 16;  // byte offset of this lane's k-chunk

  f32x4 acc[4][4] = {};

  for (int kt = 0; kt < K; kt += 64) {
    __syncthreads();
#pragma unroll
    for (int c = 0; c < 4; ++c) {
      int beta = wid * 4096 + c * 1024 + lane * 16;
      int mr = beta >> 7;
      int ib = beta & 127;
      int k = (ib ^ ((mr & 7) << 4)) >> 1;
      gl_lds16(A + (size_t)(row0 + mr) * K + kt + k, As + wid * 4096 + c * 1024);
      gl_lds16(BT + (size_t)(col0 + mr) * K + kt + k, Bs + wid * 4096 + c * 1024);
    }
    asm volatile("s_waitcnt vmcnt(0)" ::: "memory");
    __syncthreads();

    bf16x8 af[4][2], bfr[4][2];
#pragma unroll
    for (int i = 0; i < 4; ++i)
#pragma unroll
      for (int kk = 0; kk < 2; ++kk) {
        int mr = wm * 64 + i * 16 + r16;
        af[i][kk] = *(const bf16x8*)(As + mr * 128 + ((kk * 64 + kb16) ^ ((mr & 7) << 4)));
        int nr = wn * 64 + i * 16 + r16;
        bfr[i][kk] = *(const bf16x8*)(Bs + nr * 128 + ((kk * 64 + kb16) ^ ((nr & 7) << 4)));
      }
#pragma unroll
    for (int kk = 0; kk < 2; ++kk)
#pragma unroll
      for (int mi = 0; mi < 4; ++mi)
#pragma unroll
        for (int ni = 0; ni < 4; ++ni)
          acc[mi][ni] = __builtin_amdgcn_mfma_f32_16x16x32_bf16(
              af[mi][kk], bfr[ni][kk], acc[mi][ni], 0, 0, 0);
  }

  const int rg = (lane >> 4) * 4;
#pragma unroll
  for (int mi = 0; mi < 4; ++mi)
#pragma unroll
    for (int ni = 0; ni < 4; ++ni) {
      int gcol = col0 + wn * 64 + ni * 16 + r16;
      float bv = 0.f;
      if constexpr (BIAS) bv = bias[gcol];
#pragma unroll
      for (int r = 0; r < 4; ++r) {
        int grow = row0 + wm * 64 + mi * 16 + rg + r;
        float v = acc[mi][ni][r] + bv;
        if constexpr (RES) v += (float)res[(size_t)grow * N + gcol];
        if constexpr (RELU) v = fmaxf(v, 0.f);
        C[(size_t)grow * N + gcol] = (bf16)v;
      }
    }
}

// ---------------- RoPE (in-place on Q and K, bf16 internal) ----------------
__global__ void rope_k(bf16* __restrict__ Q, bf16* __restrict__ K) {
  int t = blockIdx.x * blockDim.x + threadIdx.x;  // 2*2048*16*32 threads
  int i = t & 31;
  int h = (t >> 5) & 15;
  int l = (t >> 9) & 2047;
  int bi = t >> 20;
  float inv = powf(10000.0f, -(float)i * (1.0f / 32.0f));
  float f = (float)l * inv;
  float sv, cv;
  sincosf(f, &sv, &cv);
  size_t base = ((size_t)(bi * 2048 + l)) * 1024 + h * 64 + i;
  float q1 = (float)Q[base], q2 = (float)Q[base + 32];
  Q[base] = (bf16)(q1 * cv - q2 * sv);
  Q[base + 32] = (bf16)(q1 * sv + q2 * cv);
  float k1 = (float)K[base], k2 = (float)K[base + 32];
  K[base] = (bf16)(k1 * cv - k2 * sv);
  K[base + 32] = (bf16)(k1 * sv + k2 * cv);
}

// ---------------- flash attention fwd ----------------
// grid (L/64, B*H); 4 waves/block, each wave owns 16 q-rows. KVBLK=64, dk=64.
__global__ __launch_bounds__(256, 2) void attn_k(
    const bf16* __restrict__ Qg, const bf16* __restrict__ Kg,
    const bf16* __restrict__ Vg, bf16* __restrict__ ctx) {
  __shared__ alignas(16) char Ks[64 * 128];     // [kv][d] swizzled
  __shared__ alignas(16) char Vs[64 * 128];     // [d][kv] swizzled (V^T)
  __shared__ alignas(16) char Ps[4][16 * 128];  // per-wave P [q][kv] swizzled

  const int tid = threadIdx.x;
  const int lane = tid & 63, wid = tid >> 6;
  const int bh = blockIdx.y;
  const int bi = bh >> 4, hi = bh & 15;
  const int q0 = blockIdx.x * 64;
  const int r16 = lane & 15;
  const int kb16 = (lane >> 4) * 16;

  const bf16* Qb = Qg + ((size_t)(bi * 2048 + q0 + wid * 16)) * 1024 + hi * 64;
  const bf16* Kb = Kg + ((size_t)(bi * 2048)) * 1024 + hi * 64;
  const bf16* Vb = Vg + ((size_t)(bi * 2048)) * 1024 + hi * 64;

  // Q fragments, pre-scaled by 1/sqrt(64)=0.125 (exact in bf16)
  bf16x8 qf[2];
#pragma unroll
  for (int kk = 0; kk < 2; ++kk) {
    bf16x8 t = *(const bf16x8*)(Qb + (size_t)r16 * 1024 + kk * 32 + (lane >> 4) * 8);
#pragma unroll
    for (int j = 0; j < 8; ++j) t[j] = (bf16)((float)t[j] * 0.125f);
    qf[kk] = t;
  }

  float mrun[4], lrun[4];
  f32x4 accO[4];
#pragma unroll
  for (int r = 0; r < 4; ++r) { mrun[r] = -1e30f; lrun[r] = 0.f; }
#pragma unroll
  for (int n = 0; n < 4; ++n) accO[n] = (f32x4){0.f, 0.f, 0.f, 0.f};

  for (int kv0 = 0; kv0 < 2048; kv0 += 64) {
    __syncthreads();
    // stage K tile via global_load_lds (linear dest, inverse-swizzled source)
#pragma unroll
    for (int c = 0; c < 2; ++c) {
      int beta = wid * 2048 + c * 1024 + lane * 16;
      int kv = beta >> 7;
      int ib = beta & 127;
      int d = (ib ^ ((kv & 7) << 4)) >> 1;
      gl_lds16(Kb + (size_t)(kv0 + kv) * 1024 + d, Ks + wid * 2048 + c * 1024);
    }
    // stage V transposed (reg-staged scatter)
#pragma unroll
    for (int c = 0; c < 2; ++c) {
      int e = tid + 256 * c;
      int kv = e >> 3;
      int d0 = (e & 7) * 8;
      bf16x8 vv = *(const bf16x8*)(Vb + (size_t)(kv0 + kv) * 1024 + d0);
#pragma unroll
      for (int j = 0; j < 8; ++j) {
        int d = d0 + j;
        *(bf16*)(Vs + d * 128 + ((kv * 2) ^ ((d & 7) << 4))) = vv[j];
      }
    }
    asm volatile("s_waitcnt vmcnt(0)" ::: "memory");
    __syncthreads();

    // S = Q K^T  (16 q-rows x 64 kv)
    f32x4 sc[4];
#pragma unroll
    for (int n = 0; n < 4; ++n) {
      sc[n] = (f32x4){0.f, 0.f, 0.f, 0.f};
#pragma unroll
      for (int kk = 0; kk < 2; ++kk) {
        int kvr = n * 16 + r16;
        bf16x8 kf = *(const bf16x8*)(Ks + kvr * 128 + ((kk * 64 + kb16) ^ ((kvr & 7) << 4)));
        sc[n] = __builtin_amdgcn_mfma_f32_16x16x32_bf16(qf[kk], kf, sc[n], 0, 0, 0);
      }
    }
    // online softmax: row stats via 16-lane xor-shuffle reduce
    float pm[4];
#pragma unroll
    for (int r = 0; r < 4; ++r)
      pm[r] = fmaxf(fmaxf(sc[0][r], sc[1][r]), fmaxf(sc[2][r], sc[3][r]));
#pragma unroll
    for (int mk = 1; mk < 16; mk <<= 1)
#pragma unroll
      for (int r = 0; r < 4; ++r) pm[r] = fmaxf(pm[r], __shfl_xor(pm[r], mk));
    float alpha[4], rs[4];
#pragma unroll
    for (int r = 0; r < 4; ++r) {
      float mn = fmaxf(mrun[r], pm[r]);
      alpha[r] = __expf(mrun[r] - mn);
      mrun[r] = mn;
      rs[r] = 0.f;
    }
#pragma unroll
    for (int n = 0; n < 4; ++n)
#pragma unroll
      for (int r = 0; r < 4; ++r) {
        float p = __expf(sc[n][r] - mrun[r]);
        sc[n][r] = p;
        rs[r] += p;
      }
#pragma unroll
    for (int mk = 1; mk < 16; mk <<= 1)
#pragma unroll
      for (int r = 0; r < 4; ++r) rs[r] += __shfl_xor(rs[r], mk);
#pragma unroll
    for (int r = 0; r < 4; ++r) lrun[r] = lrun[r] * alpha[r] + rs[r];

    // P (bf16) -> per-wave LDS, C-layout -> A-layout round trip
    char* Pw = Ps[wid];
#pragma unroll
    for (int n = 0; n < 4; ++n)
#pragma unroll
      for (int r = 0; r < 4; ++r) {
        int prow = (lane >> 4) * 4 + r;
        int pcol = n * 16 + r16;
        *(bf16*)(Pw + prow * 128 + ((pcol * 2) ^ ((prow & 7) << 4))) = (bf16)sc[n][r];
      }
    asm volatile("s_waitcnt lgkmcnt(0)" ::: "memory");
    __builtin_amdgcn_sched_barrier(0);
    bf16x8 pf[2];
#pragma unroll
    for (int kk = 0; kk < 2; ++kk)
      pf[kk] = *(const bf16x8*)(Pw + r16 * 128 + ((kk * 64 + kb16) ^ ((r16 & 7) << 4)));

    // rescale and accumulate O += P @ V
#pragma unroll
    for (int n = 0; n < 4; ++n)
#pragma unroll
      for (int r = 0; r < 4; ++r) accO[n][r] *= alpha[r];
#pragma unroll
    for (int n = 0; n < 4; ++n)
#pragma unroll
      for (int kk = 0; kk < 2; ++kk) {
        int d = n * 16 + r16;
        bf16x8 vf = *(const bf16x8*)(Vs + d * 128 + ((kk * 64 + kb16) ^ ((d & 7) << 4)));
        accO[n] = __builtin_amdgcn_mfma_f32_16x16x32_bf16(pf[kk], vf, accO[n], 0, 0, 0);
      }
  }

#pragma unroll
  for (int n = 0; n < 4; ++n)
#pragma unroll
    for (int r = 0; r < 4; ++r) {
      int qrow = q0 + wid * 16 + (lane >> 4) * 4 + r;
      int col = hi * 64 + n * 16 + r16;
      ctx[((size_t)(bi * 2048 + qrow)) * 1024 + col] = (bf16)(accO[n][r] / lrun[r]);
    }
}

// ------- LayerNorm over D=1024 (fp32 gamma/beta; bf16 in; out bf16 or fp32) -------
template <bool F32OUT>
__global__ void ln_k(const bf16* __restrict__ in, const float* __restrict__ gamma,
                     const float* __restrict__ beta, void* __restrict__ outv) {
  __shared__ float red[4][2];
  int row = blockIdx.x, tid = threadIdx.x;
  const bf16* x = in + (size_t)row * 1024;
  bf16x4 v = *(const bf16x4*)(x + tid * 4);
  float f[4], s = 0.f, ss = 0.f;
#pragma unroll
  for (int j = 0; j < 4; ++j) {
    f[j] = (float)v[j];
    s += f[j];
    ss += f[j] * f[j];
  }
#pragma unroll
  for (int mk = 1; mk < 64; mk <<= 1) {
    s += __shfl_xor(s, mk);
    ss += __shfl_xor(ss, mk);
  }
  int w = tid >> 6;
  if ((tid & 63) == 0) { red[w][0] = s; red[w][1] = ss; }
  __syncthreads();
  s = red[0][0] + red[1][0] + red[2][0] + red[3][0];
  ss = red[0][1] + red[1][1] + red[2][1] + red[3][1];
  float mean = s * (1.f / 1024.f);
  float var = ss * (1.f / 1024.f) - mean * mean;
  float rinv = rsqrtf(var + 1e-6f);
  f32x4 g = *(const f32x4*)(gamma + tid * 4);
  f32x4 be = *(const f32x4*)(beta + tid * 4);
  if constexpr (F32OUT) {
    f32x4 o;
#pragma unroll
    for (int j = 0; j < 4; ++j) o[j] = g[j] * (f[j] - mean) * rinv + be[j];
    *(f32x4*)((float*)outv + (size_t)row * 1024 + tid * 4) = o;
  } else {
    bf16x4 o;
#pragma unroll
    for (int j = 0; j < 4; ++j) o[j] = (bf16)(g[j] * (f[j] - mean) * rinv + be[j]);
    *(bf16x4*)((bf16*)outv + (size_t)row * 1024 + tid * 4) = o;
  }
}

extern "C" void kernel_launch(void* const* d_in, const int* in_sizes, int n_in,
                              void* d_out, int out_size, void* d_ws, size_t ws_size,
                              hipStream_t stream) {
  // Inputs fp32 (reference dtype); OUTPUT fp32 (reference output dtype!).
  const float* x = (const float*)d_in[0];
  const float* w_q = (const float*)d_in[1];
  const float* w_k = (const float*)d_in[2];
  const float* w_v = (const float*)d_in[3];
  const float* w_o = (const float*)d_in[4];
  const float* b_o = (const float*)d_in[5];
  const float* gamma1 = (const float*)d_in[6];
  const float* beta1 = (const float*)d_in[7];
  const float* gamma2 = (const float*)d_in[8];
  const float* beta2 = (const float*)d_in[9];
  const float* w1 = (const float*)d_in[10];
  const float* b1 = (const float*)d_in[11];
  const float* w2 = (const float*)d_in[12];
  const float* b2 = (const float*)d_in[13];

  // 64 MB workspace with verified-disjoint overlays:
  //  0- 2 wqT | 2- 4 wkT | 4- 6 wvT | 6- 8 woT | 8-16 w1T | 16-24 w2T
  // 24-32 xb -> hb ; 32-40 Q, 40-48 Kq, 48-56 V -> r1, 56-64 ctx
  // 32-64 ffh (Q..ctx dead at FFN1) ; 0-8 s2 (wqT..woT dead)
  char* ws = (char*)d_ws;
  const size_t MB = (size_t)1 << 20;
  bf16* wqT = (bf16*)(ws + 0 * MB);
  bf16* wkT = (bf16*)(ws + 2 * MB);
  bf16* wvT = (bf16*)(ws + 4 * MB);
  bf16* woT = (bf16*)(ws + 6 * MB);
  bf16* w1T = (bf16*)(ws + 8 * MB);
  bf16* w2T = (bf16*)(ws + 16 * MB);
  bf16* xb = (bf16*)(ws + 24 * MB);
  bf16* Q = (bf16*)(ws + 32 * MB);
  bf16* Kq = (bf16*)(ws + 40 * MB);
  bf16* V = (bf16*)(ws + 48 * MB);
  bf16* ctx = (bf16*)(ws + 56 * MB);
  bf16* r1 = (bf16*)(ws + 48 * MB);   // overlays V
  bf16* hb = (bf16*)(ws + 24 * MB);   // overlays xb
  bf16* ffh = (bf16*)(ws + 32 * MB);  // overlays Q..ctx (32MB)
  bf16* s2 = (bf16*)(ws + 0 * MB);    // overlays wqT..woT

  conv_k<<<4096, 256, 0, stream>>>(x, xb);
  dim3 tb(32, 8);
  transpose_k<<<dim3(32, 32), tb, 0, stream>>>(w_q, wqT, 1024, 1024);
  transpose_k<<<dim3(32, 32), tb, 0, stream>>>(w_k, wkT, 1024, 1024);
  transpose_k<<<dim3(32, 32), tb, 0, stream>>>(w_v, wvT, 1024, 1024);
  transpose_k<<<dim3(32, 32), tb, 0, stream>>>(w_o, woT, 1024, 1024);
  transpose_k<<<dim3(128, 32), tb, 0, stream>>>(w1, w1T, 1024, 4096);
  transpose_k<<<dim3(32, 128), tb, 0, stream>>>(w2, w2T, 4096, 1024);

  dim3 g1(8, 32);  // N=1024, M=4096
  gemm_k<false, false, false><<<g1, 256, 0, stream>>>(xb, wqT, nullptr, nullptr, Q, 4096, 1024, 1024);
  gemm_k<false, false, false><<<g1, 256, 0, stream>>>(xb, wkT, nullptr, nullptr, Kq, 4096, 1024, 1024);
  gemm_k<false, false, false><<<g1, 256, 0, stream>>>(xb, wvT, nullptr, nullptr, V, 4096, 1024, 1024);

  rope_k<<<8192, 256, 0, stream>>>(Q, Kq);

  attn_k<<<dim3(32, 32), 256, 0, stream>>>(Q, Kq, V, ctx);

  gemm_k<true, true, false><<<g1, 256, 0, stream>>>(ctx, woT, b_o, xb, r1, 4096, 1024, 1024);
  ln_k<false><<<4096, 256, 0, stream>>>(r1, gamma1, beta1, hb);
  gemm_k<true, false, true><<<dim3(32, 32), 256, 0, stream>>>(hb, w1T, b1, nullptr, ffh, 4096, 4096, 1024);
  gemm_k<true, true, false><<<g1, 256, 0, stream>>>(ffh, w2T, b2, hb, s2, 4096, 1024, 4096);
  ln_k<true><<<4096, 256, 0, stream>>>(s2, gamma2, beta2, d_out);
}

// Round 6
// 433.265 us; speedup vs baseline: 1.1991x; 1.1991x over previous
//
#include <hip/hip_runtime.h>
#include <hip/hip_bf16.h>

typedef __bf16 bf16;
typedef __bf16 bf16x8 __attribute__((ext_vector_type(8)));
typedef __bf16 bf16x4 __attribute__((ext_vector_type(4)));
typedef __bf16 bf16x2 __attribute__((ext_vector_type(2)));
typedef float f32x4 __attribute__((ext_vector_type(4)));

#define AS1 __attribute__((address_space(1)))
#define AS3 __attribute__((address_space(3)))

static __device__ __forceinline__ void gl_lds16(const bf16* g, char* lds) {
  __builtin_amdgcn_global_load_lds((const AS1 void*)g, (AS3 void*)lds, 16, 0, 0);
}

// ---------------- fp32 -> bf16 convert (x) ----------------
__global__ void conv_k(const float* __restrict__ in, bf16* __restrict__ out) {
  int t = blockIdx.x * blockDim.x + threadIdx.x;
  f32x4 v = *(const f32x4*)(in + (size_t)t * 4);
  bf16x4 o;
#pragma unroll
  for (int j = 0; j < 4; ++j) o[j] = (bf16)v[j];
  *(bf16x4*)(out + (size_t)t * 4) = o;
}

// ------- weight transpose+convert: out[c][r] = (bf16)in[r][c] -------
__global__ void transpose_k(const float* __restrict__ in, bf16* __restrict__ out,
                            int R, int C) {
  __shared__ float t[32][33];
  int c0 = blockIdx.x * 32, r0 = blockIdx.y * 32;
  int tx = threadIdx.x, ty = threadIdx.y;  // 32 x 8
#pragma unroll
  for (int i = 0; i < 32; i += 8) t[ty + i][tx] = in[(size_t)(r0 + ty + i) * C + c0 + tx];
  __syncthreads();
#pragma unroll
  for (int i = 0; i < 32; i += 8)
    out[(size_t)(c0 + ty + i) * R + r0 + tx] = (bf16)t[tx][ty + i];
}

// ---------------- GEMM: C[M,N] = A[M,K] @ BT[N,K]^T (+bias,+res,relu) ----------------
// 128x128 tile, BK=64, 4 waves (2x2), 16x16x32 bf16 MFMA. (round-4 verified)
template <bool BIAS, bool RES, bool RELU>
__global__ __launch_bounds__(256, 2) void gemm_k(
    const bf16* __restrict__ A, const bf16* __restrict__ BT,
    const float* __restrict__ bias, const bf16* __restrict__ res,
    bf16* __restrict__ C, int M, int N, int K) {
  __shared__ alignas(16) char As[128 * 128];
  __shared__ alignas(16) char Bs[128 * 128];
  const int tid = threadIdx.x;
  const int lane = tid & 63, wid = tid >> 6;
  const int wm = wid >> 1, wn = wid & 1;
  const int row0 = blockIdx.y * 128, col0 = blockIdx.x * 128;
  const int r16 = lane & 15;
  const int kb16 = (lane >> 4) * 16;

  f32x4 acc[4][4] = {};

  for (int kt = 0; kt < K; kt += 64) {
    __syncthreads();
#pragma unroll
    for (int c = 0; c < 4; ++c) {
      int beta = wid * 4096 + c * 1024 + lane * 16;
      int mr = beta >> 7;
      int ib = beta & 127;
      int k = (ib ^ ((mr & 7) << 4)) >> 1;
      gl_lds16(A + (size_t)(row0 + mr) * K + kt + k, As + wid * 4096 + c * 1024);
      gl_lds16(BT + (size_t)(col0 + mr) * K + kt + k, Bs + wid * 4096 + c * 1024);
    }
    asm volatile("s_waitcnt vmcnt(0)" ::: "memory");
    __syncthreads();

    bf16x8 af[4][2], bfr[4][2];
#pragma unroll
    for (int i = 0; i < 4; ++i)
#pragma unroll
      for (int kk = 0; kk < 2; ++kk) {
        int mr = wm * 64 + i * 16 + r16;
        af[i][kk] = *(const bf16x8*)(As + mr * 128 + ((kk * 64 + kb16) ^ ((mr & 7) << 4)));
        int nr = wn * 64 + i * 16 + r16;
        bfr[i][kk] = *(const bf16x8*)(Bs + nr * 128 + ((kk * 64 + kb16) ^ ((nr & 7) << 4)));
      }
#pragma unroll
    for (int kk = 0; kk < 2; ++kk)
#pragma unroll
      for (int mi = 0; mi < 4; ++mi)
#pragma unroll
        for (int ni = 0; ni < 4; ++ni)
          acc[mi][ni] = __builtin_amdgcn_mfma_f32_16x16x32_bf16(
              af[mi][kk], bfr[ni][kk], acc[mi][ni], 0, 0, 0);
  }

  const int rg = (lane >> 4) * 4;
#pragma unroll
  for (int mi = 0; mi < 4; ++mi)
#pragma unroll
    for (int ni = 0; ni < 4; ++ni) {
      int gcol = col0 + wn * 64 + ni * 16 + r16;
      float bv = 0.f;
      if constexpr (BIAS) bv = bias[gcol];
#pragma unroll
      for (int r = 0; r < 4; ++r) {
        int grow = row0 + wm * 64 + mi * 16 + rg + r;
        float v = acc[mi][ni][r] + bv;
        if constexpr (RES) v += (float)res[(size_t)grow * N + gcol];
        if constexpr (RELU) v = fmaxf(v, 0.f);
        C[(size_t)grow * N + gcol] = (bf16)v;
      }
    }
}

// ---------------- RoPE (in-place on Q and K, bf16 internal) ----------------
__global__ void rope_k(bf16* __restrict__ Q, bf16* __restrict__ K) {
  int t = blockIdx.x * blockDim.x + threadIdx.x;
  int i = t & 31;
  int h = (t >> 5) & 15;
  int l = (t >> 9) & 2047;
  int bi = t >> 20;
  float inv = powf(10000.0f, -(float)i * (1.0f / 32.0f));
  float f = (float)l * inv;
  float sv, cv;
  sincosf(f, &sv, &cv);
  size_t base = ((size_t)(bi * 2048 + l)) * 1024 + h * 64 + i;
  float q1 = (float)Q[base], q2 = (float)Q[base + 32];
  Q[base] = (bf16)(q1 * cv - q2 * sv);
  Q[base + 32] = (bf16)(q1 * sv + q2 * cv);
  float k1 = (float)K[base], k2 = (float)K[base + 32];
  K[base] = (bf16)(k1 * cv - k2 * sv);
  K[base + 32] = (bf16)(k1 * sv + k2 * cv);
}

// ---------------- flash attention fwd (v2) ----------------
// grid (L/64, B*H); 4 waves, each owns 16 q-rows. KVBLK=64, dk=64.
// Swapped QK^T (lane-local softmax rows), shuffle-built P frags (no P LDS),
// double-buffered K (gl_lds) + V (reg-staged, issue-early/write-late),
// one barrier per kv-tile. V^T swizzle s(d)=((d^(d>>3))&7)<<4 (write+read).
__global__ __launch_bounds__(256, 4) void attn_k(
    const bf16* __restrict__ Qg, const bf16* __restrict__ Kg,
    const bf16* __restrict__ Vg, bf16* __restrict__ ctx) {
  __shared__ alignas(16) char Ks[2][64 * 128];  // [kv][d], swz (kv&7)
  __shared__ alignas(16) char Vs[2][64 * 128];  // [d][kv], swz ((d^(d>>3))&7)

  const int tid = threadIdx.x;
  const int lane = tid & 63, wid = tid >> 6;
  const int bh = blockIdx.y;
  const int bi = bh >> 4, hi = bh & 15;
  const int q0 = blockIdx.x * 64;
  const int c = lane & 15, g = lane >> 4;
  const int kb16 = g * 16;

  const bf16* Qb = Qg + ((size_t)(bi * 2048 + q0 + wid * 16)) * 1024 + hi * 64;
  const bf16* Kb = Kg + ((size_t)(bi * 2048)) * 1024 + hi * 64;
  const bf16* Vb = Vg + ((size_t)(bi * 2048)) * 1024 + hi * 64;

  // Q fragments, pre-scaled by 1/sqrt(64)=0.125 (exact in bf16)
  bf16x8 qf[2];
#pragma unroll
  for (int kk = 0; kk < 2; ++kk) {
    bf16x8 t = *(const bf16x8*)(Qb + (size_t)c * 1024 + kk * 32 + g * 8);
#pragma unroll
    for (int j = 0; j < 8; ++j) t[j] = (bf16)((float)t[j] * 0.125f);
    qf[kk] = t;
  }

  float mrun = -1e30f, lrun = 0.f;  // stats for row q = c
  f32x4 accO[4] = {};               // O[q=4g+r][d=n*16+c]

  // prologue: stage tile 0
#pragma unroll
  for (int c2 = 0; c2 < 2; ++c2) {
    int beta = wid * 2048 + c2 * 1024 + lane * 16;
    int kv = beta >> 7, ib = beta & 127;
    int d = (ib ^ ((kv & 7) << 4)) >> 1;
    gl_lds16(Kb + (size_t)kv * 1024 + d, &Ks[0][wid * 2048 + c2 * 1024]);
  }
  {
    bf16x8 vr[2];
#pragma unroll
    for (int c2 = 0; c2 < 2; ++c2) {
      int e = tid + 256 * c2;
      vr[c2] = *(const bf16x8*)(Vb + (size_t)(e >> 3) * 1024 + (e & 7) * 8);
    }
#pragma unroll
    for (int c2 = 0; c2 < 2; ++c2) {
      int e = tid + 256 * c2;
      int kvl = e >> 3, d0 = (e & 7) * 8;
#pragma unroll
      for (int j = 0; j < 8; ++j) {
        int d = d0 + j;
        *(bf16*)(&Vs[0][d * 128 + ((kvl * 2) ^ ((((d >> 3) ^ d) & 7) << 4))]) = vr[c2][j];
      }
    }
  }
  __syncthreads();

  for (int t = 0; t < 32; ++t) {
    const int cur = t & 1, nxt = cur ^ 1;
    bf16x8 vr2[2];
    if (t + 1 < 32) {
      // issue next K tile (async gl_lds) + next V loads (regs) EARLY
#pragma unroll
      for (int c2 = 0; c2 < 2; ++c2) {
        int beta = wid * 2048 + c2 * 1024 + lane * 16;
        int kv = beta >> 7, ib = beta & 127;
        int d = (ib ^ ((kv & 7) << 4)) >> 1;
        gl_lds16(Kb + (size_t)((t + 1) * 64 + kv) * 1024 + d,
                 &Ks[nxt][wid * 2048 + c2 * 1024]);
      }
#pragma unroll
      for (int c2 = 0; c2 < 2; ++c2) {
        int e = tid + 256 * c2;
        vr2[c2] = *(const bf16x8*)(Vb + (size_t)((t + 1) * 64 + (e >> 3)) * 1024 + (e & 7) * 8);
      }
    }

    // S^T = K Q^T : lane holds S[q=c][kv = n*16 + 4g + r]
    f32x4 sc[4];
#pragma unroll
    for (int n = 0; n < 4; ++n) {
      sc[n] = (f32x4){0.f, 0.f, 0.f, 0.f};
#pragma unroll
      for (int kk = 0; kk < 2; ++kk) {
        int kvr = n * 16 + c;
        bf16x8 kf = *(const bf16x8*)(&Ks[cur][kvr * 128 + ((kk * 64 + kb16) ^ ((kvr & 7) << 4))]);
        sc[n] = __builtin_amdgcn_mfma_f32_16x16x32_bf16(kf, qf[kk], sc[n], 0, 0, 0);
      }
    }

    // online softmax, lane-local row
    float pm = sc[0][0];
#pragma unroll
    for (int n = 0; n < 4; ++n)
#pragma unroll
      for (int r = 0; r < 4; ++r) pm = fmaxf(pm, sc[n][r]);
    pm = fmaxf(pm, __shfl_xor(pm, 16));
    pm = fmaxf(pm, __shfl_xor(pm, 32));
    float mn = fmaxf(mrun, pm);
    float alpha = __expf(mrun - mn);
    mrun = mn;
    float rs = 0.f;
#pragma unroll
    for (int n = 0; n < 4; ++n)
#pragma unroll
      for (int r = 0; r < 4; ++r) {
        float pv = __expf(sc[n][r] - mn);
        sc[n][r] = pv;
        rs += pv;
      }
    rs += __shfl_xor(rs, 16);
    rs += __shfl_xor(rs, 32);
    lrun = lrun * alpha + rs;

    // pack P pairs: P2[n][w] = bf16x2{p[n][2w], p[n][2w+1]}
    int P2[4][2];
#pragma unroll
    for (int n = 0; n < 4; ++n)
#pragma unroll
      for (int w = 0; w < 2; ++w) {
        bf16x2 h;
        h[0] = (bf16)sc[n][2 * w];
        h[1] = (bf16)sc[n][2 * w + 1];
        P2[n][w] = __builtin_bit_cast(int, h);
      }

    // build A-frag of P via shuffles: lane needs P[q=c][kv=kk*32+8g+0..7]
    const int sA = c + ((lane & 16) << 1);  // c + 32*(g&1)
    const int sB = sA + 16;
    const bool hb = (lane & 32) != 0;  // g>=2 -> n = 2kk+1
    bf16x8 pf[2];
#pragma unroll
    for (int kk = 0; kk < 2; ++kk) {
      int n0 = 2 * kk, n1 = 2 * kk + 1;
      int a0 = __shfl(P2[n0][0], sA), a1 = __shfl(P2[n0][1], sA);
      int a2 = __shfl(P2[n0][0], sB), a3 = __shfl(P2[n0][1], sB);
      int b0 = __shfl(P2[n1][0], sA), b1 = __shfl(P2[n1][1], sA);
      int b2 = __shfl(P2[n1][0], sB), b3 = __shfl(P2[n1][1], sB);
      int4 wv;
      wv.x = hb ? b0 : a0;
      wv.y = hb ? b1 : a1;
      wv.z = hb ? b2 : a2;
      wv.w = hb ? b3 : a3;
      pf[kk] = __builtin_bit_cast(bf16x8, wv);
    }

    // rescale accO by alpha of its q-rows (q_local = 4g+r)
    float alo[4];
#pragma unroll
    for (int r = 0; r < 4; ++r) alo[r] = __shfl(alpha, 4 * g + r);
#pragma unroll
    for (int n = 0; n < 4; ++n)
#pragma unroll
      for (int r = 0; r < 4; ++r) accO[n][r] *= alo[r];

    // O += P @ V
#pragma unroll
    for (int n = 0; n < 4; ++n)
#pragma unroll
      for (int kk = 0; kk < 2; ++kk) {
        int d = n * 16 + c;
        bf16x8 vf = *(const bf16x8*)(&Vs[cur][d * 128 + ((kk * 64 + kb16) ^ ((((d >> 3) ^ d) & 7) << 4))]);
        accO[n] = __builtin_amdgcn_mfma_f32_16x16x32_bf16(pf[kk], vf, accO[n], 0, 0, 0);
      }

    // write next V tile (loads auto-waited via register dep), then barrier
    if (t + 1 < 32) {
#pragma unroll
      for (int c2 = 0; c2 < 2; ++c2) {
        int e = tid + 256 * c2;
        int kvl = e >> 3, d0 = (e & 7) * 8;
#pragma unroll
        for (int j = 0; j < 8; ++j) {
          int d = d0 + j;
          *(bf16*)(&Vs[nxt][d * 128 + ((kvl * 2) ^ ((((d >> 3) ^ d) & 7) << 4))]) = vr2[c2][j];
        }
      }
    }
    __syncthreads();  // drains gl_lds (vmcnt) + LDS writes; next tile ready
  }

  // epilogue
  float lo[4];
#pragma unroll
  for (int r = 0; r < 4; ++r) lo[r] = __shfl(lrun, 4 * g + r);
#pragma unroll
  for (int n = 0; n < 4; ++n)
#pragma unroll
    for (int r = 0; r < 4; ++r) {
      int qrow = q0 + wid * 16 + g * 4 + r;
      int col = hi * 64 + n * 16 + c;
      ctx[((size_t)(bi * 2048 + qrow)) * 1024 + col] = (bf16)(accO[n][r] / lo[r]);
    }
}

// ------- LayerNorm over D=1024 (fp32 gamma/beta; bf16 in; out bf16 or fp32) -------
template <bool F32OUT>
__global__ void ln_k(const bf16* __restrict__ in, const float* __restrict__ gamma,
                     const float* __restrict__ beta, void* __restrict__ outv) {
  __shared__ float red[4][2];
  int row = blockIdx.x, tid = threadIdx.x;
  const bf16* x = in + (size_t)row * 1024;
  bf16x4 v = *(const bf16x4*)(x + tid * 4);
  float f[4], s = 0.f, ss = 0.f;
#pragma unroll
  for (int j = 0; j < 4; ++j) {
    f[j] = (float)v[j];
    s += f[j];
    ss += f[j] * f[j];
  }
#pragma unroll
  for (int mk = 1; mk < 64; mk <<= 1) {
    s += __shfl_xor(s, mk);
    ss += __shfl_xor(ss, mk);
  }
  int w = tid >> 6;
  if ((tid & 63) == 0) { red[w][0] = s; red[w][1] = ss; }
  __syncthreads();
  s = red[0][0] + red[1][0] + red[2][0] + red[3][0];
  ss = red[0][1] + red[1][1] + red[2][1] + red[3][1];
  float mean = s * (1.f / 1024.f);
  float var = ss * (1.f / 1024.f) - mean * mean;
  float rinv = rsqrtf(var + 1e-6f);
  f32x4 g = *(const f32x4*)(gamma + tid * 4);
  f32x4 be = *(const f32x4*)(beta + tid * 4);
  if constexpr (F32OUT) {
    f32x4 o;
#pragma unroll
    for (int j = 0; j < 4; ++j) o[j] = g[j] * (f[j] - mean) * rinv + be[j];
    *(f32x4*)((float*)outv + (size_t)row * 1024 + tid * 4) = o;
  } else {
    bf16x4 o;
#pragma unroll
    for (int j = 0; j < 4; ++j) o[j] = (bf16)(g[j] * (f[j] - mean) * rinv + be[j]);
    *(bf16x4*)((bf16*)outv + (size_t)row * 1024 + tid * 4) = o;
  }
}

extern "C" void kernel_launch(void* const* d_in, const int* in_sizes, int n_in,
                              void* d_out, int out_size, void* d_ws, size_t ws_size,
                              hipStream_t stream) {
  const float* x = (const float*)d_in[0];
  const float* w_q = (const float*)d_in[1];
  const float* w_k = (const float*)d_in[2];
  const float* w_v = (const float*)d_in[3];
  const float* w_o = (const float*)d_in[4];
  const float* b_o = (const float*)d_in[5];
  const float* gamma1 = (const float*)d_in[6];
  const float* beta1 = (const float*)d_in[7];
  const float* gamma2 = (const float*)d_in[8];
  const float* beta2 = (const float*)d_in[9];
  const float* w1 = (const float*)d_in[10];
  const float* b1 = (const float*)d_in[11];
  const float* w2 = (const float*)d_in[12];
  const float* b2 = (const float*)d_in[13];

  // 64 MB workspace with verified-disjoint overlays
  char* ws = (char*)d_ws;
  const size_t MB = (size_t)1 << 20;
  bf16* wqT = (bf16*)(ws + 0 * MB);
  bf16* wkT = (bf16*)(ws + 2 * MB);
  bf16* wvT = (bf16*)(ws + 4 * MB);
  bf16* woT = (bf16*)(ws + 6 * MB);
  bf16* w1T = (bf16*)(ws + 8 * MB);
  bf16* w2T = (bf16*)(ws + 16 * MB);
  bf16* xb = (bf16*)(ws + 24 * MB);
  bf16* Q = (bf16*)(ws + 32 * MB);
  bf16* Kq = (bf16*)(ws + 40 * MB);
  bf16* V = (bf16*)(ws + 48 * MB);
  bf16* ctx = (bf16*)(ws + 56 * MB);
  bf16* r1 = (bf16*)(ws + 48 * MB);   // overlays V
  bf16* hb = (bf16*)(ws + 24 * MB);   // overlays xb
  bf16* ffh = (bf16*)(ws + 32 * MB);  // overlays Q..ctx (32MB)
  bf16* s2 = (bf16*)(ws + 0 * MB);    // overlays wqT..woT

  conv_k<<<4096, 256, 0, stream>>>(x, xb);
  dim3 tb(32, 8);
  transpose_k<<<dim3(32, 32), tb, 0, stream>>>(w_q, wqT, 1024, 1024);
  transpose_k<<<dim3(32, 32), tb, 0, stream>>>(w_k, wkT, 1024, 1024);
  transpose_k<<<dim3(32, 32), tb, 0, stream>>>(w_v, wvT, 1024, 1024);
  transpose_k<<<dim3(32, 32), tb, 0, stream>>>(w_o, woT, 1024, 1024);
  transpose_k<<<dim3(128, 32), tb, 0, stream>>>(w1, w1T, 1024, 4096);
  transpose_k<<<dim3(32, 128), tb, 0, stream>>>(w2, w2T, 4096, 1024);

  dim3 g1(8, 32);  // N=1024, M=4096
  gemm_k<false, false, false><<<g1, 256, 0, stream>>>(xb, wqT, nullptr, nullptr, Q, 4096, 1024, 1024);
  gemm_k<false, false, false><<<g1, 256, 0, stream>>>(xb, wkT, nullptr, nullptr, Kq, 4096, 1024, 1024);
  gemm_k<false, false, false><<<g1, 256, 0, stream>>>(xb, wvT, nullptr, nullptr, V, 4096, 1024, 1024);

  rope_k<<<8192, 256, 0, stream>>>(Q, Kq);

  attn_k<<<dim3(32, 32), 256, 0, stream>>>(Q, Kq, V, ctx);

  gemm_k<true, true, false><<<g1, 256, 0, stream>>>(ctx, woT, b_o, xb, r1, 4096, 1024, 1024);
  ln_k<false><<<4096, 256, 0, stream>>>(r1, gamma1, beta1, hb);
  gemm_k<true, false, true><<<dim3(32, 32), 256, 0, stream>>>(hb, w1T, b1, nullptr, ffh, 4096, 4096, 1024);
  gemm_k<true, true, false><<<g1, 256, 0, stream>>>(ffh, w2T, b2, hb, s2, 4096, 1024, 4096);
  ln_k<true><<<4096, 256, 0, stream>>>(s2, gamma2, beta2, d_out);
}

// Round 8
// 377.573 us; speedup vs baseline: 1.3759x; 1.1475x over previous
//
#include <hip/hip_runtime.h>
#include <hip/hip_bf16.h>

typedef __bf16 bf16;
typedef __bf16 bf16x8 __attribute__((ext_vector_type(8)));
typedef __bf16 bf16x4 __attribute__((ext_vector_type(4)));
typedef __bf16 bf16x2 __attribute__((ext_vector_type(2)));
typedef float f32x4 __attribute__((ext_vector_type(4)));

#define AS1 __attribute__((address_space(1)))
#define AS3 __attribute__((address_space(3)))

static __device__ __forceinline__ void gl_lds16(const bf16* g, char* lds) {
  __builtin_amdgcn_global_load_lds((const AS1 void*)g, (AS3 void*)lds, 16, 0, 0);
}

// ---------------- prep: conv x->xb + all weight transposes, one launch ----------------
static __device__ __forceinline__ void transp(const float* __restrict__ in,
                                              bf16* __restrict__ out, int R, int C,
                                              int idx, int tid, float (*t)[33]) {
  int nbx = C >> 5;
  int bx = idx % nbx, by = idx / nbx;
  int c0 = bx * 32, r0 = by * 32;
  int tx = tid & 31, ty = tid >> 5;  // 32 x 8
#pragma unroll
  for (int i = 0; i < 32; i += 8) t[ty + i][tx] = in[(size_t)(r0 + ty + i) * C + c0 + tx];
  __syncthreads();
#pragma unroll
  for (int i = 0; i < 32; i += 8)
    out[(size_t)(c0 + ty + i) * R + r0 + tx] = (bf16)t[tx][ty + i];
}

__global__ void prep_k(const float* __restrict__ x, const float* __restrict__ w_q,
                       const float* __restrict__ w_k, const float* __restrict__ w_v,
                       const float* __restrict__ w_o, const float* __restrict__ w1,
                       const float* __restrict__ w2, bf16* __restrict__ xb,
                       bf16* __restrict__ wqkvT, bf16* __restrict__ woT,
                       bf16* __restrict__ w1T, bf16* __restrict__ w2T) {
  __shared__ float t[32][33];
  int b = blockIdx.x, tid = threadIdx.x;
  if (b < 4096) {
    int i = b * 256 + tid;
    f32x4 v = *(const f32x4*)(x + (size_t)i * 4);
    bf16x4 o;
#pragma unroll
    for (int j = 0; j < 4; ++j) o[j] = (bf16)v[j];
    *(bf16x4*)(xb + (size_t)i * 4) = o;
  } else if (b < 5120) {
    transp(w_q, wqkvT, 1024, 1024, b - 4096, tid, t);
  } else if (b < 6144) {
    transp(w_k, wqkvT + 1024 * 1024, 1024, 1024, b - 5120, tid, t);
  } else if (b < 7168) {
    transp(w_v, wqkvT + 2048 * 1024, 1024, 1024, b - 6144, tid, t);
  } else if (b < 8192) {
    transp(w_o, woT, 1024, 1024, b - 7168, tid, t);
  } else if (b < 12288) {
    transp(w1, w1T, 1024, 4096, b - 8192, tid, t);
  } else {
    transp(w2, w2T, 4096, 1024, b - 12288, tid, t);
  }
}

// ---------------- GEMM v2: 2-phase double-buffered, XCD-swizzled 1D grid ----------------
// C[M,N] = A[M,K] @ BT[N,K]^T (+bias,+res,relu). 128x128 tile, BK=64, 4 waves.
// LDS element (r,k) at byte r*128 + ((k*2)^((r&7)<<4)); gl_lds dest linear,
// global source inverse-swizzled. Stage tile t+1 while computing t; one barrier/step.
template <bool BIAS, bool RES, bool RELU>
__global__ __launch_bounds__(256, 2) void gemm_k(
    const bf16* __restrict__ A, const bf16* __restrict__ BT,
    const float* __restrict__ bias, const bf16* __restrict__ res,
    bf16* __restrict__ C, int M, int N, int K, int nbx) {
  __shared__ alignas(16) char As[2][128 * 128];
  __shared__ alignas(16) char Bs[2][128 * 128];
  const int tid = threadIdx.x;
  const int lane = tid & 63, wid = tid >> 6;
  const int wm = wid >> 1, wn = wid & 1;
  const int nwg = gridDim.x;  // always %8==0 here
  const int wg = (blockIdx.x & 7) * (nwg >> 3) + (blockIdx.x >> 3);
  const int row0 = (wg / nbx) * 128, col0 = (wg % nbx) * 128;
  const int r16 = lane & 15;
  const int kb16 = (lane >> 4) * 16;

  f32x4 acc[4][4] = {};
  const int nk = K >> 6;

  int smr[4], sk[4];
#pragma unroll
  for (int c = 0; c < 4; ++c) {
    int beta = wid * 4096 + c * 1024 + lane * 16;
    smr[c] = beta >> 7;
    sk[c] = ((beta & 127) ^ ((smr[c] & 7) << 4)) >> 1;
  }

  // prologue: stage tile 0 into buf0
#pragma unroll
  for (int c = 0; c < 4; ++c) {
    gl_lds16(A + (size_t)(row0 + smr[c]) * K + sk[c], &As[0][wid * 4096 + c * 1024]);
    gl_lds16(BT + (size_t)(col0 + smr[c]) * K + sk[c], &Bs[0][wid * 4096 + c * 1024]);
  }
  __syncthreads();  // drains vmcnt before first reads

  for (int t = 0; t < nk; ++t) {
    const int cur = t & 1, nxt = cur ^ 1;
    if (t + 1 < nk) {
      const int kt = (t + 1) << 6;
#pragma unroll
      for (int c = 0; c < 4; ++c) {
        gl_lds16(A + (size_t)(row0 + smr[c]) * K + kt + sk[c], &As[nxt][wid * 4096 + c * 1024]);
        gl_lds16(BT + (size_t)(col0 + smr[c]) * K + kt + sk[c], &Bs[nxt][wid * 4096 + c * 1024]);
      }
    }
    bf16x8 af[4][2], bfr[4][2];
#pragma unroll
    for (int i = 0; i < 4; ++i)
#pragma unroll
      for (int kk = 0; kk < 2; ++kk) {
        int mr = wm * 64 + i * 16 + r16;
        af[i][kk] = *(const bf16x8*)(&As[cur][mr * 128 + ((kk * 64 + kb16) ^ ((mr & 7) << 4))]);
        int nr = wn * 64 + i * 16 + r16;
        bfr[i][kk] = *(const bf16x8*)(&Bs[cur][nr * 128 + ((kk * 64 + kb16) ^ ((nr & 7) << 4))]);
      }
#pragma unroll
    for (int kk = 0; kk < 2; ++kk)
#pragma unroll
      for (int mi = 0; mi < 4; ++mi)
#pragma unroll
        for (int ni = 0; ni < 4; ++ni)
          acc[mi][ni] = __builtin_amdgcn_mfma_f32_16x16x32_bf16(
              af[mi][kk], bfr[ni][kk], acc[mi][ni], 0, 0, 0);
    __syncthreads();  // drains stage(t+1) vmcnt + all reads of cur done
  }

  const int rg = (lane >> 4) * 4;
#pragma unroll
  for (int mi = 0; mi < 4; ++mi)
#pragma unroll
    for (int ni = 0; ni < 4; ++ni) {
      int gcol = col0 + wn * 64 + ni * 16 + r16;
      float bv = 0.f;
      if constexpr (BIAS) bv = bias[gcol];
#pragma unroll
      for (int r = 0; r < 4; ++r) {
        int grow = row0 + wm * 64 + mi * 16 + rg + r;
        float v = acc[mi][ni][r] + bv;
        if constexpr (RES) v += (float)res[(size_t)grow * N + gcol];
        if constexpr (RELU) v = fmaxf(v, 0.f);
        C[(size_t)grow * N + gcol] = (bf16)v;
      }
    }
}

// ---------------- RoPE (in-place on Q,K parts of fused QKV buffer) ----------------
__global__ void rope_k(bf16* __restrict__ QKV) {
  int t = blockIdx.x * blockDim.x + threadIdx.x;
  int i = t & 31;
  int h = (t >> 5) & 15;
  int l = (t >> 9) & 2047;
  int bi = t >> 20;
  float inv = powf(10000.0f, -(float)i * (1.0f / 32.0f));
  float f = (float)l * inv;
  float sv, cv;
  sincosf(f, &sv, &cv);
  size_t base = ((size_t)(bi * 2048 + l)) * 3072 + h * 64 + i;
  float q1 = (float)QKV[base], q2 = (float)QKV[base + 32];
  QKV[base] = (bf16)(q1 * cv - q2 * sv);
  QKV[base + 32] = (bf16)(q1 * sv + q2 * cv);
  float k1 = (float)QKV[base + 1024], k2 = (float)QKV[base + 1056];
  QKV[base + 1024] = (bf16)(k1 * cv - k2 * sv);
  QKV[base + 1056] = (bf16)(k1 * sv + k2 * cv);
}

// ---------------- flash attention fwd (v2, QKV stride 3072) ----------------
__global__ __launch_bounds__(256, 4) void attn_k(
    const bf16* __restrict__ QKV, bf16* __restrict__ ctx) {
  __shared__ alignas(16) char Ks[2][64 * 128];  // [kv][d], swz (kv&7)
  __shared__ alignas(16) char Vs[2][64 * 128];  // [d][kv], swz ((d^(d>>3))&7)

  const int tid = threadIdx.x;
  const int lane = tid & 63, wid = tid >> 6;
  const int bh = blockIdx.y;
  const int bi = bh >> 4, hi = bh & 15;
  const int q0 = blockIdx.x * 64;
  const int c = lane & 15, g = lane >> 4;
  const int kb16 = g * 16;
  const int LD = 3072;

  const bf16* Qb = QKV + ((size_t)(bi * 2048 + q0 + wid * 16)) * LD + hi * 64;
  const bf16* Kb = QKV + ((size_t)(bi * 2048)) * LD + 1024 + hi * 64;
  const bf16* Vb = QKV + ((size_t)(bi * 2048)) * LD + 2048 + hi * 64;

  bf16x8 qf[2];
#pragma unroll
  for (int kk = 0; kk < 2; ++kk) {
    bf16x8 t = *(const bf16x8*)(Qb + (size_t)c * LD + kk * 32 + g * 8);
#pragma unroll
    for (int j = 0; j < 8; ++j) t[j] = (bf16)((float)t[j] * 0.125f);
    qf[kk] = t;
  }

  float mrun = -1e30f, lrun = 0.f;
  f32x4 accO[4] = {};

  // prologue: stage tile 0
#pragma unroll
  for (int c2 = 0; c2 < 2; ++c2) {
    int beta = wid * 2048 + c2 * 1024 + lane * 16;
    int kv = beta >> 7, ib = beta & 127;
    int d = (ib ^ ((kv & 7) << 4)) >> 1;
    gl_lds16(Kb + (size_t)kv * LD + d, &Ks[0][wid * 2048 + c2 * 1024]);
  }
  {
    bf16x8 vr[2];
#pragma unroll
    for (int c2 = 0; c2 < 2; ++c2) {
      int e = tid + 256 * c2;
      vr[c2] = *(const bf16x8*)(Vb + (size_t)(e >> 3) * LD + (e & 7) * 8);
    }
#pragma unroll
    for (int c2 = 0; c2 < 2; ++c2) {
      int e = tid + 256 * c2;
      int kvl = e >> 3, d0 = (e & 7) * 8;
#pragma unroll
      for (int j = 0; j < 8; ++j) {
        int d = d0 + j;
        *(bf16*)(&Vs[0][d * 128 + ((kvl * 2) ^ ((((d >> 3) ^ d) & 7) << 4))]) = vr[c2][j];
      }
    }
  }
  __syncthreads();

  for (int t = 0; t < 32; ++t) {
    const int cur = t & 1, nxt = cur ^ 1;
    bf16x8 vr2[2];
    if (t + 1 < 32) {
#pragma unroll
      for (int c2 = 0; c2 < 2; ++c2) {
        int beta = wid * 2048 + c2 * 1024 + lane * 16;
        int kv = beta >> 7, ib = beta & 127;
        int d = (ib ^ ((kv & 7) << 4)) >> 1;
        gl_lds16(Kb + (size_t)((t + 1) * 64 + kv) * LD + d,
                 &Ks[nxt][wid * 2048 + c2 * 1024]);
      }
#pragma unroll
      for (int c2 = 0; c2 < 2; ++c2) {
        int e = tid + 256 * c2;
        vr2[c2] = *(const bf16x8*)(Vb + (size_t)((t + 1) * 64 + (e >> 3)) * LD + (e & 7) * 8);
      }
    }

    // S^T = K Q^T : lane holds S[q=c][kv = n*16 + 4g + r]
    f32x4 sc[4];
    __builtin_amdgcn_s_setprio(1);
#pragma unroll
    for (int n = 0; n < 4; ++n) {
      sc[n] = (f32x4){0.f, 0.f, 0.f, 0.f};
#pragma unroll
      for (int kk = 0; kk < 2; ++kk) {
        int kvr = n * 16 + c;
        bf16x8 kf = *(const bf16x8*)(&Ks[cur][kvr * 128 + ((kk * 64 + kb16) ^ ((kvr & 7) << 4))]);
        sc[n] = __builtin_amdgcn_mfma_f32_16x16x32_bf16(kf, qf[kk], sc[n], 0, 0, 0);
      }
    }
    __builtin_amdgcn_s_setprio(0);

    // online softmax, lane-local row
    float pm = sc[0][0];
#pragma unroll
    for (int n = 0; n < 4; ++n)
#pragma unroll
      for (int r = 0; r < 4; ++r) pm = fmaxf(pm, sc[n][r]);
    pm = fmaxf(pm, __shfl_xor(pm, 16));
    pm = fmaxf(pm, __shfl_xor(pm, 32));
    float mn = fmaxf(mrun, pm);
    float alpha = __expf(mrun - mn);
    mrun = mn;
    float rs = 0.f;
#pragma unroll
    for (int n = 0; n < 4; ++n)
#pragma unroll
      for (int r = 0; r < 4; ++r) {
        float pv = __expf(sc[n][r] - mn);
        sc[n][r] = pv;
        rs += pv;
      }
    rs += __shfl_xor(rs, 16);
    rs += __shfl_xor(rs, 32);
    lrun = lrun * alpha + rs;

    int P2[4][2];
#pragma unroll
    for (int n = 0; n < 4; ++n)
#pragma unroll
      for (int w = 0; w < 2; ++w) {
        bf16x2 h;
        h[0] = (bf16)sc[n][2 * w];
        h[1] = (bf16)sc[n][2 * w + 1];
        P2[n][w] = __builtin_bit_cast(int, h);
      }

    const int sA = c + ((lane & 16) << 1);
    const int sB = sA + 16;
    const bool hb = (lane & 32) != 0;
    bf16x8 pf[2];
#pragma unroll
    for (int kk = 0; kk < 2; ++kk) {
      int n0 = 2 * kk, n1 = 2 * kk + 1;
      int a0 = __shfl(P2[n0][0], sA), a1 = __shfl(P2[n0][1], sA);
      int a2 = __shfl(P2[n0][0], sB), a3 = __shfl(P2[n0][1], sB);
      int b0 = __shfl(P2[n1][0], sA), b1 = __shfl(P2[n1][1], sA);
      int b2 = __shfl(P2[n1][0], sB), b3 = __shfl(P2[n1][1], sB);
      int4 wv;
      wv.x = hb ? b0 : a0;
      wv.y = hb ? b1 : a1;
      wv.z = hb ? b2 : a2;
      wv.w = hb ? b3 : a3;
      pf[kk] = __builtin_bit_cast(bf16x8, wv);
    }

    float alo[4];
#pragma unroll
    for (int r = 0; r < 4; ++r) alo[r] = __shfl(alpha, 4 * g + r);
#pragma unroll
    for (int n = 0; n < 4; ++n)
#pragma unroll
      for (int r = 0; r < 4; ++r) accO[n][r] *= alo[r];

    __builtin_amdgcn_s_setprio(1);
#pragma unroll
    for (int n = 0; n < 4; ++n)
#pragma unroll
      for (int kk = 0; kk < 2; ++kk) {
        int d = n * 16 + c;
        bf16x8 vf = *(const bf16x8*)(&Vs[cur][d * 128 + ((kk * 64 + kb16) ^ ((((d >> 3) ^ d) & 7) << 4))]);
        accO[n] = __builtin_amdgcn_mfma_f32_16x16x32_bf16(pf[kk], vf, accO[n], 0, 0, 0);
      }
    __builtin_amdgcn_s_setprio(0);

    if (t + 1 < 32) {
#pragma unroll
      for (int c2 = 0; c2 < 2; ++c2) {
        int e = tid + 256 * c2;
        int kvl = e >> 3, d0 = (e & 7) * 8;
#pragma unroll
        for (int j = 0; j < 8; ++j) {
          int d = d0 + j;
          *(bf16*)(&Vs[nxt][d * 128 + ((kvl * 2) ^ ((((d >> 3) ^ d) & 7) << 4))]) = vr2[c2][j];
        }
      }
    }
    __syncthreads();
  }

  float lo[4];
#pragma unroll
  for (int r = 0; r < 4; ++r) lo[r] = __shfl(lrun, 4 * g + r);
#pragma unroll
  for (int n = 0; n < 4; ++n)
#pragma unroll
    for (int r = 0; r < 4; ++r) {
      int qrow = q0 + wid * 16 + g * 4 + r;
      int col = hi * 64 + n * 16 + c;
      ctx[((size_t)(bi * 2048 + qrow)) * 1024 + col] = (bf16)(accO[n][r] / lo[r]);
    }
}

// ------- LayerNorm over D=1024 (fp32 gamma/beta; bf16 in; out bf16 or fp32) -------
template <bool F32OUT>
__global__ void ln_k(const bf16* __restrict__ in, const float* __restrict__ gamma,
                     const float* __restrict__ beta, void* __restrict__ outv) {
  __shared__ float red[4][2];
  int row = blockIdx.x, tid = threadIdx.x;
  const bf16* x = in + (size_t)row * 1024;
  bf16x4 v = *(const bf16x4*)(x + tid * 4);
  float f[4], s = 0.f, ss = 0.f;
#pragma unroll
  for (int j = 0; j < 4; ++j) {
    f[j] = (float)v[j];
    s += f[j];
    ss += f[j] * f[j];
  }
#pragma unroll
  for (int mk = 1; mk < 64; mk <<= 1) {
    s += __shfl_xor(s, mk);
    ss += __shfl_xor(ss, mk);
  }
  int w = tid >> 6;
  if ((tid & 63) == 0) { red[w][0] = s; red[w][1] = ss; }
  __syncthreads();
  s = red[0][0] + red[1][0] + red[2][0] + red[3][0];
  ss = red[0][1] + red[1][1] + red[2][1] + red[3][1];
  float mean = s * (1.f / 1024.f);
  float var = ss * (1.f / 1024.f) - mean * mean;
  float rinv = rsqrtf(var + 1e-6f);
  f32x4 g = *(const f32x4*)(gamma + tid * 4);
  f32x4 be = *(const f32x4*)(beta + tid * 4);
  if constexpr (F32OUT) {
    f32x4 o;
#pragma unroll
    for (int j = 0; j < 4; ++j) o[j] = g[j] * (f[j] - mean) * rinv + be[j];
    *(f32x4*)((float*)outv + (size_t)row * 1024 + tid * 4) = o;
  } else {
    bf16x4 o;
#pragma unroll
    for (int j = 0; j < 4; ++j) o[j] = (bf16)(g[j] * (f[j] - mean) * rinv + be[j]);
    *(bf16x4*)((bf16*)outv + (size_t)row * 1024 + tid * 4) = o;
  }
}

extern "C" void kernel_launch(void* const* d_in, const int* in_sizes, int n_in,
                              void* d_out, int out_size, void* d_ws, size_t ws_size,
                              hipStream_t stream) {
  const float* x = (const float*)d_in[0];
  const float* w_q = (const float*)d_in[1];
  const float* w_k = (const float*)d_in[2];
  const float* w_v = (const float*)d_in[3];
  const float* w_o = (const float*)d_in[4];
  const float* b_o = (const float*)d_in[5];
  const float* gamma1 = (const float*)d_in[6];
  const float* beta1 = (const float*)d_in[7];
  const float* gamma2 = (const float*)d_in[8];
  const float* beta2 = (const float*)d_in[9];
  const float* w1 = (const float*)d_in[10];
  const float* b1 = (const float*)d_in[11];
  const float* w2 = (const float*)d_in[12];
  const float* b2 = (const float*)d_in[13];

  // 80 MB workspace, verified-disjoint overlays:
  //  0- 6 wqkvT | 6- 8 woT | 8-16 w1T | 16-24 w2T | 24-32 xb
  // 32-56 QKV (dead after attn) | 56-64 ctx (dead after attn-out)
  // 32-40 r1 (overlays QKV) | 40-48 hb (overlays QKV)
  // 48-80 ffh | 0-8 s2 (wqkvT/woT dead by FFN2)
  char* ws = (char*)d_ws;
  const size_t MB = (size_t)1 << 20;
  bf16* wqkvT = (bf16*)(ws + 0 * MB);
  bf16* woT = (bf16*)(ws + 6 * MB);
  bf16* w1T = (bf16*)(ws + 8 * MB);
  bf16* w2T = (bf16*)(ws + 16 * MB);
  bf16* xb = (bf16*)(ws + 24 * MB);
  bf16* QKV = (bf16*)(ws + 32 * MB);
  bf16* ctx = (bf16*)(ws + 56 * MB);
  bf16* r1 = (bf16*)(ws + 32 * MB);
  bf16* hb = (bf16*)(ws + 40 * MB);
  bf16* ffh = (bf16*)(ws + 48 * MB);
  bf16* s2 = (bf16*)(ws + 0 * MB);

  prep_k<<<16384, 256, 0, stream>>>(x, w_q, w_k, w_v, w_o, w1, w2,
                                    xb, wqkvT, woT, w1T, w2T);

  // fused QKV: [4096,3072] = xb @ wqkvT^T
  gemm_k<false, false, false><<<768, 256, 0, stream>>>(
      xb, wqkvT, nullptr, nullptr, QKV, 4096, 3072, 1024, 24);

  rope_k<<<8192, 256, 0, stream>>>(QKV);

  attn_k<<<dim3(32, 32), 256, 0, stream>>>(QKV, ctx);

  gemm_k<true, true, false><<<256, 256, 0, stream>>>(
      ctx, woT, b_o, xb, r1, 4096, 1024, 1024, 8);
  ln_k<false><<<4096, 256, 0, stream>>>(r1, gamma1, beta1, hb);
  gemm_k<true, false, true><<<1024, 256, 0, stream>>>(
      hb, w1T, b1, nullptr, ffh, 4096, 4096, 1024, 32);
  gemm_k<true, true, false><<<256, 256, 0, stream>>>(
      ffh, w2T, b2, hb, s2, 4096, 1024, 4096, 8);
  ln_k<true><<<4096, 256, 0, stream>>>(s2, gamma2, beta2, d_out);
}